// Round 4
// baseline (974.185 us; speedup 1.0000x reference)
//
#include <hip/hip_runtime.h>
#include <math.h>

#define HID 128
#define DHD 32
#define N_T 90

__device__ __forceinline__ float gelu_f(float x) {
    return 0.5f * x * (1.0f + erff(x * 0.70710678118654752f));
}
__device__ __forceinline__ float softplus_f(float x) {
    return fmaxf(x, 0.0f) + log1pf(expf(-fabsf(x)));
}

// ---------------- signature features ----------------
template<int P>
__device__ __forceinline__ void sig_substep(float c1[4], float c2[16], float s3[64],
                                            float d0, float d1) {
    float h00 = 0.5f * d0 * d0, h01 = 0.5f * d0 * d1, h11 = 0.5f * d1 * d1;
#pragma unroll
    for (int a = 0; a < 4; ++a) {
#pragma unroll
        for (int b = 0; b < 4; ++b) {
            float c2ab = c2[a * 4 + b];
            s3[a * 16 + b * 4 + P + 0] += c2ab * d0;
            s3[a * 16 + b * 4 + P + 1] += c2ab * d1;
        }
    }
#pragma unroll
    for (int a = 0; a < 4; ++a) {
        float c = c1[a];
        s3[a * 16 + (P + 0) * 4 + (P + 0)] += c * h00;
        s3[a * 16 + (P + 0) * 4 + (P + 1)] += c * h01;
        s3[a * 16 + (P + 1) * 4 + (P + 0)] += c * h01;
        s3[a * 16 + (P + 1) * 4 + (P + 1)] += c * h11;
    }
    const float i6 = 0.16666666666666666f;
    float t000 = d0 * d0 * d0 * i6, t001 = d0 * d0 * d1 * i6;
    float t011 = d0 * d1 * d1 * i6, t111 = d1 * d1 * d1 * i6;
    s3[(P + 0) * 16 + (P + 0) * 4 + (P + 0)] += t000;
    s3[(P + 0) * 16 + (P + 0) * 4 + (P + 1)] += t001;
    s3[(P + 0) * 16 + (P + 1) * 4 + (P + 0)] += t001;
    s3[(P + 0) * 16 + (P + 1) * 4 + (P + 1)] += t011;
    s3[(P + 1) * 16 + (P + 0) * 4 + (P + 0)] += t001;
    s3[(P + 1) * 16 + (P + 0) * 4 + (P + 1)] += t011;
    s3[(P + 1) * 16 + (P + 1) * 4 + (P + 0)] += t011;
    s3[(P + 1) * 16 + (P + 1) * 4 + (P + 1)] += t111;
#pragma unroll
    for (int a = 0; a < 4; ++a) {
        float c = c1[a];
        c2[a * 4 + P + 0] += c * d0;
        c2[a * 4 + P + 1] += c * d1;
    }
    c2[(P + 0) * 4 + (P + 0)] += h00;
    c2[(P + 0) * 4 + (P + 1)] += h01;
    c2[(P + 1) * 4 + (P + 0)] += h01;
    c2[(P + 1) * 4 + (P + 1)] += h11;
    c1[P + 0] += d0;
    c1[P + 1] += d1;
}

__global__ void sig_kernel(const float* __restrict__ nf, float* __restrict__ X, int nn) {
    int node = blockIdx.x * blockDim.x + threadIdx.x;
    int win = blockIdx.y;
    if (node >= nn) return;
    int w = (win == 0) ? 7 : (win == 1) ? 28 : 90;
    const float* xp = nf + (size_t)node * (N_T * 2) + (size_t)(N_T - w) * 2;
    float c1[4] = {0.f, 0.f, 0.f, 0.f};
    float c2[16] = {0.f};
    float s3[64] = {0.f};
    float p0 = xp[0], p1 = xp[1];
    for (int i = 1; i < w; ++i) {
        float n0 = xp[i * 2], n1 = xp[i * 2 + 1];
        float d0 = n0 - p0, d1 = n1 - p1;
        sig_substep<0>(c1, c2, s3, d0, d1);
        sig_substep<2>(c1, c2, s3, d0, d1);
        p0 = n0; p1 = n1;
    }
    float* o = X + (size_t)node * 292 + win * 84;
#pragma unroll
    for (int k = 0; k < 4; ++k) o[k] = c1[k];
#pragma unroll
    for (int k = 0; k < 16; ++k) o[4 + k] = c2[k];
#pragma unroll
    for (int k = 0; k < 64; ++k) o[20 + k] = s3[k];
}

// ---------------- embeddings -> X[:, 252:292] ----------------
__global__ void emb_kernel(float* __restrict__ X,
                           const int* __restrict__ store_id, const int* __restrict__ dept_id,
                           const int* __restrict__ cat_id, const int* __restrict__ state_id,
                           const int* __restrict__ item_id,
                           const float* __restrict__ e_store, const float* __restrict__ e_dept,
                           const float* __restrict__ e_cat, const float* __restrict__ e_state,
                           const float* __restrict__ e_item, int nn) {
    int n = blockIdx.x * blockDim.x + threadIdx.x;
    if (n >= nn) return;
    float* o = X + (size_t)n * 292 + 252;
    const float* p;
    p = e_store + store_id[n] * 8;
#pragma unroll
    for (int j = 0; j < 8; ++j) o[j] = p[j];
    p = e_dept + dept_id[n] * 8;
#pragma unroll
    for (int j = 0; j < 8; ++j) o[8 + j] = p[j];
    p = e_cat + cat_id[n] * 4;
#pragma unroll
    for (int j = 0; j < 4; ++j) o[16 + j] = p[j];
    p = e_state + state_id[n] * 4;
#pragma unroll
    for (int j = 0; j < 4; ++j) o[20 + j] = p[j];
    p = e_item + item_id[n] * 16;
#pragma unroll
    for (int j = 0; j < 16; ++j) o[24 + j] = p[j];
}

// ============================================================================
// Double-buffered f32 GEMM, BM=64 BN=128 BK=32, 256 threads, 4x8 microtile.
// ONE barrier per K-step; global loads for step t+1 in flight under compute(t).
// Dual-output: blockIdx.y < nby1 uses (B1,bias1,C1,N1,act1) with column block
// blockIdx.y; otherwise (B2,bias2,C2,N2,act2) with column block y-nby1.
// Lets q = h@W and r = h@Wres share one dispatch (and one A-fetch).
// ============================================================================
__global__ __launch_bounds__(256)
void gemm_db_kernel(const float* __restrict__ A, int M, int K,
                    const float* __restrict__ B1, const float* __restrict__ bias1,
                    float* __restrict__ C1, int N1, int act1, int nby1,
                    const float* __restrict__ B2, const float* __restrict__ bias2,
                    float* __restrict__ C2, int N2, int act2) {
    __shared__ float As[2][32][68];    // [buf][k][m]
    __shared__ float Bs[2][32][132];   // [buf][k][n]
    int tid = threadIdx.x;
    int bm = blockIdx.x * 64;
    int by = blockIdx.y;

    const float* B = B1; const float* bias = bias1; float* C = C1;
    int N = N1, act = act1, colbase;
    if (by < nby1) {
        colbase = by * 128;
    } else {
        B = B2; bias = bias2; C = C2; N = N2; act = act2;
        colbase = (by - nby1) * 128;
    }

    // load mapping
    int arow = tid >> 3;               // 0..31  (A rows arow, arow+32)
    int akq  = (tid & 7) * 4;          // A k-offset
    int bk   = tid >> 5;               // 0..7   (B k rows bk, bk+8, bk+16, bk+24)
    int bnq  = (tid & 31) * 4;         // B col offset (within 128-col block)
    // compute mapping
    int tx = tid & 15, ty = tid >> 4;  // cols tx*8..+7, rows ty*4..+3

    float areg[2][4];
    float breg[4][4];
    float acc[4][8] = {};

    int T = (K + 31) / 32;

    // ---- load tile t into regs ----
    auto load_tile = [&](int t) {
        int k0 = t * 32;
#pragma unroll
        for (int i = 0; i < 2; ++i) {
            int row = bm + arow + i * 32;
            int col = k0 + akq;
            if (row < M && col + 4 <= K) {
                float4 v = *(const float4*)(A + (size_t)row * K + col);
                areg[i][0] = v.x; areg[i][1] = v.y; areg[i][2] = v.z; areg[i][3] = v.w;
            } else {
#pragma unroll
                for (int u = 0; u < 4; ++u)
                    areg[i][u] = (row < M && col + u < K) ? A[(size_t)row * K + col + u] : 0.f;
            }
        }
#pragma unroll
        for (int i = 0; i < 4; ++i) {
            int krow = k0 + bk + i * 8;
            int col = colbase + bnq;
            if (krow < K && col + 4 <= N) {
                float4 v = *(const float4*)(B + (size_t)krow * N + col);
                breg[i][0] = v.x; breg[i][1] = v.y; breg[i][2] = v.z; breg[i][3] = v.w;
            } else {
#pragma unroll
                for (int u = 0; u < 4; ++u)
                    breg[i][u] = (krow < K && col + u < N) ? B[(size_t)krow * N + col + u] : 0.f;
            }
        }
    };

    auto store_tile = [&](int d) {
#pragma unroll
        for (int i = 0; i < 2; ++i)
#pragma unroll
            for (int u = 0; u < 4; ++u)
                As[d][akq + u][arow + i * 32] = areg[i][u];
#pragma unroll
        for (int i = 0; i < 4; ++i)
            *(float4*)&Bs[d][bk + i * 8][bnq] = make_float4(breg[i][0], breg[i][1],
                                                            breg[i][2], breg[i][3]);
    };

    load_tile(0);
    for (int t = 0; t < T; ++t) {
        int d = t & 1;
        store_tile(d);
        if (t + 1 < T) load_tile(t + 1);
        __syncthreads();
#pragma unroll
        for (int kk = 0; kk < 32; ++kk) {
            float4 a = *(const float4*)&As[d][kk][ty * 4];
            float4 b0 = *(const float4*)&Bs[d][kk][tx * 8];
            float4 b1 = *(const float4*)&Bs[d][kk][tx * 8 + 4];
            float aa[4] = {a.x, a.y, a.z, a.w};
            float bb[8] = {b0.x, b0.y, b0.z, b0.w, b1.x, b1.y, b1.z, b1.w};
#pragma unroll
            for (int i = 0; i < 4; ++i)
#pragma unroll
                for (int j = 0; j < 8; ++j) acc[i][j] += aa[i] * bb[j];
        }
    }

    // epilogue
#pragma unroll
    for (int i = 0; i < 4; ++i) {
        int row = bm + ty * 4 + i;
        if (row >= M) continue;
        int col0 = colbase + tx * 8;
        float v[8];
#pragma unroll
        for (int j = 0; j < 8; ++j) {
            float x = acc[i][j];
            int col = col0 + j;
            if (bias && col < N) x += bias[col];
            if (act == 1) x = gelu_f(x);
            v[j] = x;
        }
        if (col0 + 8 <= N) {
            *(float4*)(C + (size_t)row * N + col0) = make_float4(v[0], v[1], v[2], v[3]);
            *(float4*)(C + (size_t)row * N + col0 + 4) = make_float4(v[4], v[5], v[6], v[7]);
        } else {
#pragma unroll
            for (int j = 0; j < 8; ++j)
                if (col0 + j < N) C[(size_t)row * N + col0 + j] = v[j];
        }
    }
}

// ---------------- fused gelu + layernorm (in-place, 128 cols) ----------------
__global__ void gelu_ln_kernel(float* __restrict__ h, const float* __restrict__ g,
                               const float* __restrict__ b) {
    int row = blockIdx.x, t = threadIdx.x;
    float* hp = h + (size_t)row * HID;
    float x = gelu_f(hp[t]);
    __shared__ float red[2];
    float s = x;
#pragma unroll
    for (int off = 32; off > 0; off >>= 1) s += __shfl_xor(s, off);
    if ((t & 63) == 0) red[t >> 6] = s;
    __syncthreads();
    float mean = (red[0] + red[1]) * (1.0f / 128.0f);
    float d = x - mean;
    float vs = d * d;
    __syncthreads();
#pragma unroll
    for (int off = 32; off > 0; off >>= 1) vs += __shfl_xor(vs, off);
    if ((t & 63) == 0) red[t >> 6] = vs;
    __syncthreads();
    float var = (red[0] + red[1]) * (1.0f / 128.0f);
    hp[t] = d / sqrtf(var + 1e-5f) * g[t] + b[t];
}

// ---------------- CSR build (dst-indexed) ----------------
__global__ void hist_kernel(const int* __restrict__ dst, int* __restrict__ deg, int e) {
    int i = blockIdx.x * blockDim.x + threadIdx.x;
    if (i < e) atomicAdd(&deg[dst[i]], 1);
}

__global__ void scan_kernel(const int* __restrict__ deg, int* __restrict__ row_start,
                            int* __restrict__ cursor, int n) {
    __shared__ int wsum[16];
    __shared__ int chunk_total;
    int t = threadIdx.x;
    int lane = t & 63, wv = t >> 6;
    int carry = 0;
    for (int base = 0; base < n; base += 8192) {
        int idx0 = base + t * 8;
        int v[8];
        int s = 0;
#pragma unroll
        for (int u = 0; u < 8; ++u) {
            int d = (idx0 + u < n) ? deg[idx0 + u] : 0;
            v[u] = s;
            s += d;
        }
        int ws = s;
#pragma unroll
        for (int off = 1; off < 64; off <<= 1) {
            int u2 = __shfl_up(ws, off);
            if (lane >= off) ws += u2;
        }
        if (lane == 63) wsum[wv] = ws;
        __syncthreads();
        if (t == 0) {
            int a = 0;
#pragma unroll
            for (int k = 0; k < 16; ++k) {
                int tmp = wsum[k];
                wsum[k] = a;
                a += tmp;
            }
            chunk_total = a;
        }
        __syncthreads();
        int excl = ws - s + wsum[wv] + carry;
#pragma unroll
        for (int u = 0; u < 8; ++u) {
            if (idx0 + u < n) {
                row_start[idx0 + u] = excl + v[u];
                cursor[idx0 + u] = excl + v[u];
            }
        }
        carry += chunk_total;
        __syncthreads();
    }
    if (t == 0) row_start[n] = carry;
}

__global__ void scatter_kernel(const int* __restrict__ src, const int* __restrict__ dst,
                               const int* __restrict__ et, int* __restrict__ cursor,
                               int* __restrict__ csr_src, int* __restrict__ csr_de, int e) {
    int i = blockIdx.x * blockDim.x + threadIdx.x;
    if (i < e) {
        int d = dst[i];
        int pos = atomicAdd(&cursor[d], 1);
        csr_src[pos] = src[i];
        csr_de[pos] = d | (et[i] << 20);
    }
}

// ---------------- per-(node,head) attention dots ----------------
__global__ void esed_kernel(const float* __restrict__ q, const float* __restrict__ asrc,
                            const float* __restrict__ adst, float* __restrict__ es,
                            float* __restrict__ ed, int nn) {
    int idx = blockIdx.x * blockDim.x + threadIdx.x;
    if (idx >= nn * 4) return;
    int n = idx >> 2, hh = idx & 3;
    const float* qp = q + (size_t)n * HID + hh * DHD;
    const float* ap = asrc + hh * DHD;
    const float* dp = adst + hh * DHD;
    float s = 0.f, d = 0.f;
#pragma unroll
    for (int k = 0; k < DHD; ++k) {
        float qv = qp[k];
        s += qv * ap[k];
        d += qv * dp[k];
    }
    es[idx] = s;
    ed[idx] = d;
}

// ---------------- per-CSR-slot logits (4 heads) ----------------
__global__ void lg_kernel(const int* __restrict__ csr_src, const int* __restrict__ csr_de,
                          const float* __restrict__ es, const float* __restrict__ ed,
                          const float* __restrict__ etb, float* __restrict__ lg_csr, int e) {
    int pos = blockIdx.x * blockDim.x + threadIdx.x;
    if (pos >= e) return;
    int s = csr_src[pos];
    int de = csr_de[pos];
    int d = de & 0xFFFFF;
    int et = de >> 20;
    float4 esv = *(const float4*)(es + (size_t)s * 4);
    float4 edv = *(const float4*)(ed + (size_t)d * 4);
    float4 bv  = *(const float4*)(etb + (size_t)et * 4);
    float l0 = esv.x + edv.x + bv.x;
    float l1 = esv.y + edv.y + bv.y;
    float l2 = esv.z + edv.z + bv.z;
    float l3 = esv.w + edv.w + bv.w;
    l0 = l0 > 0.f ? l0 : 0.2f * l0;
    l1 = l1 > 0.f ? l1 : 0.2f * l1;
    l2 = l2 > 0.f ? l2 : 0.2f * l2;
    l3 = l3 > 0.f ? l3 : 0.2f * l3;
    *(float4*)(lg_csr + (size_t)pos * 4) = make_float4(l0, l1, l2, l3);
}

// ---------------- per-(node,head) softmax max/denominator ----------------
__global__ void mden_kernel(const float* __restrict__ lg_csr, const int* __restrict__ row_start,
                            float* __restrict__ m_arr, float* __restrict__ den_arr, int nn) {
    int idx = blockIdx.x * blockDim.x + threadIdx.x;
    if (idx >= nn * 4) return;
    int n = idx >> 2, hh = idx & 3;
    int e0 = row_start[n], e1 = row_start[n + 1];
    float m = -INFINITY;
    for (int e = e0; e < e1; ++e) m = fmaxf(m, lg_csr[(size_t)e * 4 + hh]);
    if (e0 == e1) m = 0.f;
    float den = 0.f;
    for (int e = e0; e < e1; ++e) den += expf(lg_csr[(size_t)e * 4 + hh] - m);
    m_arr[idx] = m;
    den_arr[idx] = den;
}

// ---------------- per-(edge,head) alpha (in-place over lg) ----------------
__global__ void alpha_kernel(float* __restrict__ lg_csr, const int* __restrict__ csr_de,
                             const float* __restrict__ m_arr, const float* __restrict__ den_arr,
                             int e) {
    int idx = blockIdx.x * blockDim.x + threadIdx.x;
    if (idx >= e * 4) return;
    int pos = idx >> 2, hh = idx & 3;
    int d = csr_de[pos] & 0xFFFFF;
    float a = expf(lg_csr[idx] - m_arr[(size_t)d * 4 + hh]) /
              (den_arr[(size_t)d * 4 + hh] + 1e-9f);
    lg_csr[idx] = a;
}

// ---------------- GAT aggregation: pure alpha * q gather-FMA ----------------
__global__ void gat_agg_kernel(const float* __restrict__ q, const float* __restrict__ r,
                               const float* __restrict__ alpha_csr,
                               const int* __restrict__ row_start, const int* __restrict__ csr_src,
                               float* __restrict__ hout, int nn) {
    int n = blockIdx.x;
    int t = threadIdx.x;
    int hh = t >> 5;
    int e0 = row_start[n], e1 = row_start[n + 1];
    float acc = 0.f;
    for (int e = e0; e < e1; ++e) {
        int s = csr_src[e];
        float al = alpha_csr[(size_t)e * 4 + hh];
        acc += al * q[(size_t)s * HID + t];
    }
    float v = acc + r[(size_t)n * HID + t];
    hout[(size_t)n * HID + t] = v > 0.f ? v : expm1f(v);
}

// ---------------- final scaling + clip ----------------
__global__ void final_kernel(const float* __restrict__ y, const float* __restrict__ hs,
                             const float* __restrict__ gs, const int* __restrict__ dept_ids,
                             const float* __restrict__ hm, float* __restrict__ out, int nn) {
    int idx = blockIdx.x * blockDim.x + threadIdx.x;
    if (idx >= nn * 28) return;
    int n = idx / 28, j = idx - n * 28;
    float v = y[idx] * softplus_f(hs[j]) * softplus_f(gs[dept_ids[n]]);
    float hi = 20.0f * hm[n];
    out[idx] = fminf(fmaxf(v, 0.0f), hi);
}

extern "C" void kernel_launch(void* const* d_in, const int* in_sizes, int n_in,
                              void* d_out, int out_size, void* d_ws, size_t ws_size,
                              hipStream_t stream) {
    const float* nf       = (const float*)d_in[0];
    const int*   eidx     = (const int*)d_in[1];
    const int*   etype    = (const int*)d_in[2];
    const int*   store_id = (const int*)d_in[3];
    const int*   dept_id  = (const int*)d_in[4];
    const int*   cat_id   = (const int*)d_in[5];
    const int*   state_id = (const int*)d_in[6];
    const int*   item_id  = (const int*)d_in[7];
    const int*   dept_ids = (const int*)d_in[8];
    const float* hm       = (const float*)d_in[9];
    const float* e_store  = (const float*)d_in[10];
    const float* e_dept   = (const float*)d_in[11];
    const float* e_cat    = (const float*)d_in[12];
    const float* e_state  = (const float*)d_in[13];
    const float* e_item   = (const float*)d_in[14];
    const float* fusion_W = (const float*)d_in[15];
    const float* fusion_b = (const float*)d_in[16];
    const float* ln_g     = (const float*)d_in[17];
    const float* ln_b     = (const float*)d_in[18];
    const float* gat_W    = (const float*)d_in[19];
    const float* gat_b    = (const float*)d_in[20];
    const float* gat_asrc = (const float*)d_in[21];
    const float* gat_adst = (const float*)d_in[22];
    const float* gat_et   = (const float*)d_in[23];
    const float* gat_Wres = (const float*)d_in[24];
    const float* pW1      = (const float*)d_in[25];
    const float* pb1      = (const float*)d_in[26];
    const float* pW2      = (const float*)d_in[27];
    const float* pb2      = (const float*)d_in[28];
    const float* pW3      = (const float*)d_in[29];
    const float* pb3      = (const float*)d_in[30];
    const float* hs       = (const float*)d_in[31];
    const float* gs       = (const float*)d_in[32];

    const int nn = in_sizes[3];   // 30490
    const int ee = in_sizes[2];   // 487840
    const int* src = eidx;
    const int* dst = eidx + ee;

    // workspace layout
    float* ws = (float*)d_ws;
    float* X   = ws;                               // nn x 292
    float* h   = X + (size_t)nn * 292;             // nn x 128
    float* q   = h + (size_t)nn * 128;             // nn x 128
    float* r   = q + (size_t)nn * 128;             // nn x 128
    float* t2  = r + (size_t)nn * 128;             // nn x 256
    float* es  = t2 + (size_t)nn * 256;            // nn x 4
    float* ed  = es + (size_t)nn * 4;              // nn x 4
    float* m_a = ed + (size_t)nn * 4;              // nn x 4
    float* d_a = m_a + (size_t)nn * 4;             // nn x 4
    float* lg  = d_a + (size_t)nn * 4;             // ee x 4
    int* deg       = (int*)(lg + (size_t)ee * 4);  // nn
    int* row_start = deg + nn;                     // nn+1
    int* cursor    = row_start + nn + 1;           // nn
    int* csr_src   = cursor + nn;                  // ee
    int* csr_de    = csr_src + ee;                 // ee
    float* t1 = X;                                 // reuse
    float* y  = q;                                 // reuse

    const int gx = (nn + 63) / 64;

    // --- CSR build ---
    hipMemsetAsync(deg, 0, nn * sizeof(int), stream);
    hist_kernel<<<(ee + 255) / 256, 256, 0, stream>>>(dst, deg, ee);
    scan_kernel<<<1, 1024, 0, stream>>>(deg, row_start, cursor, nn);
    scatter_kernel<<<(ee + 255) / 256, 256, 0, stream>>>(src, dst, etype, cursor,
                                                         csr_src, csr_de, ee);

    // --- features ---
    dim3 sg((nn + 255) / 256, 3);
    sig_kernel<<<sg, 256, 0, stream>>>(nf, X, nn);
    emb_kernel<<<(nn + 255) / 256, 256, 0, stream>>>(X, store_id, dept_id, cat_id, state_id,
                                                     item_id, e_store, e_dept, e_cat, e_state,
                                                     e_item, nn);

    // --- fusion + LN ---
    gemm_db_kernel<<<dim3(gx, 1), 256, 0, stream>>>(
        X, nn, 292, fusion_W, fusion_b, h, 128, 0, 1,
        nullptr, nullptr, nullptr, 0, 0);
    gelu_ln_kernel<<<nn, 128, 0, stream>>>(h, ln_g, ln_b);

    // --- 3 GAT layers ---
    for (int l = 0; l < 3; ++l) {
        // q = h@W + b  and  r = h@Wres in ONE dispatch (shared A)
        gemm_db_kernel<<<dim3(gx, 2), 256, 0, stream>>>(
            h, nn, 128,
            gat_W + (size_t)l * 128 * 128, gat_b + l * 128, q, 128, 0, 1,
            gat_Wres + (size_t)l * 128 * 128, nullptr, r, 128, 0);
        esed_kernel<<<(nn * 4 + 255) / 256, 256, 0, stream>>>(q, gat_asrc + l * 128,
                                                              gat_adst + l * 128, es, ed, nn);
        lg_kernel<<<(ee + 255) / 256, 256, 0, stream>>>(csr_src, csr_de, es, ed,
                                                        gat_et + l * 12, lg, ee);
        mden_kernel<<<(nn * 4 + 255) / 256, 256, 0, stream>>>(lg, row_start, m_a, d_a, nn);
        alpha_kernel<<<(ee * 4 + 255) / 256, 256, 0, stream>>>(lg, csr_de, m_a, d_a, ee);
        gat_agg_kernel<<<nn, 128, 0, stream>>>(q, r, lg, row_start, csr_src, h, nn);
    }

    // --- prediction MLP ---
    gemm_db_kernel<<<dim3(gx, 2), 256, 0, stream>>>(
        h, nn, 128, pW1, pb1, t1, 256, 1, 2,
        nullptr, nullptr, nullptr, 0, 0);
    gemm_db_kernel<<<dim3(gx, 2), 256, 0, stream>>>(
        t1, nn, 256, pW2, pb2, t2, 256, 1, 2,
        nullptr, nullptr, nullptr, 0, 0);
    gemm_db_kernel<<<dim3(gx, 1), 256, 0, stream>>>(
        t2, nn, 256, pW3, pb3, y, 28, 0, 1,
        nullptr, nullptr, nullptr, 0, 0);
    final_kernel<<<(nn * 28 + 255) / 256, 256, 0, stream>>>(y, hs, gs, dept_ids, hm,
                                                            (float*)d_out, nn);
}

// Round 9
// 869.744 us; speedup vs baseline: 1.1201x; 1.1201x over previous
//
#include <hip/hip_runtime.h>
#include <math.h>

#define HID 128
#define DHD 32
#define N_T 90

__device__ __forceinline__ float gelu_f(float x) {
    return 0.5f * x * (1.0f + erff(x * 0.70710678118654752f));
}
__device__ __forceinline__ float softplus_f(float x) {
    return fmaxf(x, 0.0f) + log1pf(expf(-fabsf(x)));
}

// ---------------- signature features ----------------
template<int P>
__device__ __forceinline__ void sig_substep(float c1[4], float c2[16], float s3[64],
                                            float d0, float d1) {
    float h00 = 0.5f * d0 * d0, h01 = 0.5f * d0 * d1, h11 = 0.5f * d1 * d1;
#pragma unroll
    for (int a = 0; a < 4; ++a) {
#pragma unroll
        for (int b = 0; b < 4; ++b) {
            float c2ab = c2[a * 4 + b];
            s3[a * 16 + b * 4 + P + 0] += c2ab * d0;
            s3[a * 16 + b * 4 + P + 1] += c2ab * d1;
        }
    }
#pragma unroll
    for (int a = 0; a < 4; ++a) {
        float c = c1[a];
        s3[a * 16 + (P + 0) * 4 + (P + 0)] += c * h00;
        s3[a * 16 + (P + 0) * 4 + (P + 1)] += c * h01;
        s3[a * 16 + (P + 1) * 4 + (P + 0)] += c * h01;
        s3[a * 16 + (P + 1) * 4 + (P + 1)] += c * h11;
    }
    const float i6 = 0.16666666666666666f;
    float t000 = d0 * d0 * d0 * i6, t001 = d0 * d0 * d1 * i6;
    float t011 = d0 * d1 * d1 * i6, t111 = d1 * d1 * d1 * i6;
    s3[(P + 0) * 16 + (P + 0) * 4 + (P + 0)] += t000;
    s3[(P + 0) * 16 + (P + 0) * 4 + (P + 1)] += t001;
    s3[(P + 0) * 16 + (P + 1) * 4 + (P + 0)] += t001;
    s3[(P + 0) * 16 + (P + 1) * 4 + (P + 1)] += t011;
    s3[(P + 1) * 16 + (P + 0) * 4 + (P + 0)] += t001;
    s3[(P + 1) * 16 + (P + 0) * 4 + (P + 1)] += t011;
    s3[(P + 1) * 16 + (P + 1) * 4 + (P + 0)] += t011;
    s3[(P + 1) * 16 + (P + 1) * 4 + (P + 1)] += t111;
#pragma unroll
    for (int a = 0; a < 4; ++a) {
        float c = c1[a];
        c2[a * 4 + P + 0] += c * d0;
        c2[a * 4 + P + 1] += c * d1;
    }
    c2[(P + 0) * 4 + (P + 0)] += h00;
    c2[(P + 0) * 4 + (P + 1)] += h01;
    c2[(P + 1) * 4 + (P + 0)] += h01;
    c2[(P + 1) * 4 + (P + 1)] += h11;
    c1[P + 0] += d0;
    c1[P + 1] += d1;
}

__global__ void sig_kernel(const float* __restrict__ nf, float* __restrict__ X, int nn) {
    int node = blockIdx.x * blockDim.x + threadIdx.x;
    int win = blockIdx.y;
    if (node >= nn) return;
    int w = (win == 0) ? 7 : (win == 1) ? 28 : 90;
    const float* xp = nf + (size_t)node * (N_T * 2) + (size_t)(N_T - w) * 2;
    float c1[4] = {0.f, 0.f, 0.f, 0.f};
    float c2[16] = {0.f};
    float s3[64] = {0.f};
    float p0 = xp[0], p1 = xp[1];
    for (int i = 1; i < w; ++i) {
        float n0 = xp[i * 2], n1 = xp[i * 2 + 1];
        float d0 = n0 - p0, d1 = n1 - p1;
        sig_substep<0>(c1, c2, s3, d0, d1);
        sig_substep<2>(c1, c2, s3, d0, d1);
        p0 = n0; p1 = n1;
    }
    float* o = X + (size_t)node * 292 + win * 84;
#pragma unroll
    for (int k = 0; k < 4; ++k) o[k] = c1[k];
#pragma unroll
    for (int k = 0; k < 16; ++k) o[4 + k] = c2[k];
#pragma unroll
    for (int k = 0; k < 64; ++k) o[20 + k] = s3[k];
}

// ---------------- embeddings -> X[:, 252:292] ----------------
__global__ void emb_kernel(float* __restrict__ X,
                           const int* __restrict__ store_id, const int* __restrict__ dept_id,
                           const int* __restrict__ cat_id, const int* __restrict__ state_id,
                           const int* __restrict__ item_id,
                           const float* __restrict__ e_store, const float* __restrict__ e_dept,
                           const float* __restrict__ e_cat, const float* __restrict__ e_state,
                           const float* __restrict__ e_item, int nn) {
    int n = blockIdx.x * blockDim.x + threadIdx.x;
    if (n >= nn) return;
    float* o = X + (size_t)n * 292 + 252;
    const float* p;
    p = e_store + store_id[n] * 8;
#pragma unroll
    for (int j = 0; j < 8; ++j) o[j] = p[j];
    p = e_dept + dept_id[n] * 8;
#pragma unroll
    for (int j = 0; j < 8; ++j) o[8 + j] = p[j];
    p = e_cat + cat_id[n] * 4;
#pragma unroll
    for (int j = 0; j < 4; ++j) o[16 + j] = p[j];
    p = e_state + state_id[n] * 4;
#pragma unroll
    for (int j = 0; j < 4; ++j) o[20 + j] = p[j];
    p = e_item + item_id[n] * 16;
#pragma unroll
    for (int j = 0; j < 16; ++j) o[24 + j] = p[j];
}

// ============================================================================
// Double-buffered f32 GEMM, BM=64 BN=128 BK=16, 256 threads, 4x(4+4) microtile
// with column split {tx*4, tx*4+64}. All LDS access patterns verified <=2
// words/bank per wave (free per m136). ONE barrier per K-step.
// Dual-output: blockIdx.y < nby1 -> (B1,bias1,C1,N1,act1), col block y;
// else (B2,...), col block y-nby1. q/r GEMMs share one A-fetch.
// ============================================================================
__global__ __launch_bounds__(256)
void gemm_db_kernel(const float* __restrict__ A, int M, int K,
                    const float* __restrict__ B1, const float* __restrict__ bias1,
                    float* __restrict__ C1, int N1, int act1, int nby1,
                    const float* __restrict__ B2, const float* __restrict__ bias2,
                    float* __restrict__ C2, int N2, int act2) {
    __shared__ float As[2][16][68];    // [buf][k][m]
    __shared__ float Bs[2][16][132];   // [buf][k][n]
    int tid = threadIdx.x;
    int bm = blockIdx.x * 64;
    int by = blockIdx.y;

    const float* B = B1; const float* bias = bias1; float* C = C1;
    int N = N1, act = act1, colbase;
    if (by < nby1) {
        colbase = by * 128;
    } else {
        B = B2; bias = bias2; C = C2; N = N2; act = act2;
        colbase = (by - nby1) * 128;
    }

    // load mapping
    int ar = tid >> 2, ac = (tid & 3) * 4;     // A: row ar (0..63), k-cols ac..ac+3
    int bk = tid >> 4, bcol = (tid & 15) * 4;  // B: k-row bk (0..15), cols bcol, bcol+64
    // compute mapping
    int tx = tid & 15, ty = tid >> 4;          // rows ty*4..+3, cols tx*4..+3 & tx*4+64..+67

    float areg[4], breg0[4], breg1[4];
    float acc[4][8] = {};

    int T = (K + 15) / 16;

    auto load_tile = [&](int t) {
        int k0 = t * 16;
        int row = bm + ar;
        int col = k0 + ac;
        if (row < M && col + 4 <= K) {
            float4 v = *(const float4*)(A + (size_t)row * K + col);
            areg[0] = v.x; areg[1] = v.y; areg[2] = v.z; areg[3] = v.w;
        } else {
#pragma unroll
            for (int u = 0; u < 4; ++u)
                areg[u] = (row < M && col + u < K) ? A[(size_t)row * K + col + u] : 0.f;
        }
        int krow = k0 + bk;
        int c0 = colbase + bcol;
        if (krow < K && c0 + 4 <= N) {
            float4 v = *(const float4*)(B + (size_t)krow * N + c0);
            breg0[0] = v.x; breg0[1] = v.y; breg0[2] = v.z; breg0[3] = v.w;
        } else {
#pragma unroll
            for (int u = 0; u < 4; ++u)
                breg0[u] = (krow < K && c0 + u < N) ? B[(size_t)krow * N + c0 + u] : 0.f;
        }
        int c1 = c0 + 64;
        if (krow < K && c1 + 4 <= N) {
            float4 v = *(const float4*)(B + (size_t)krow * N + c1);
            breg1[0] = v.x; breg1[1] = v.y; breg1[2] = v.z; breg1[3] = v.w;
        } else {
#pragma unroll
            for (int u = 0; u < 4; ++u)
                breg1[u] = (krow < K && c1 + u < N) ? B[(size_t)krow * N + c1 + u] : 0.f;
        }
    };

    auto store_tile = [&](int d) {
#pragma unroll
        for (int u = 0; u < 4; ++u)
            As[d][ac + u][ar] = areg[u];
        *(float4*)&Bs[d][bk][bcol] = make_float4(breg0[0], breg0[1], breg0[2], breg0[3]);
        *(float4*)&Bs[d][bk][bcol + 64] = make_float4(breg1[0], breg1[1], breg1[2], breg1[3]);
    };

    load_tile(0);
    for (int t = 0; t < T; ++t) {
        int d = t & 1;
        store_tile(d);
        if (t + 1 < T) load_tile(t + 1);
        __syncthreads();
#pragma unroll
        for (int kk = 0; kk < 16; ++kk) {
            float4 a  = *(const float4*)&As[d][kk][ty * 4];
            float4 b0 = *(const float4*)&Bs[d][kk][tx * 4];
            float4 b1 = *(const float4*)&Bs[d][kk][tx * 4 + 64];
            float aa[4] = {a.x, a.y, a.z, a.w};
            float bb[8] = {b0.x, b0.y, b0.z, b0.w, b1.x, b1.y, b1.z, b1.w};
#pragma unroll
            for (int i = 0; i < 4; ++i)
#pragma unroll
                for (int j = 0; j < 8; ++j) acc[i][j] += aa[i] * bb[j];
        }
    }

    // epilogue: two float4 stores per row (cols tx*4, tx*4+64)
#pragma unroll
    for (int i = 0; i < 4; ++i) {
        int row = bm + ty * 4 + i;
        if (row >= M) continue;
#pragma unroll
        for (int half = 0; half < 2; ++half) {
            int col0 = colbase + tx * 4 + half * 64;
            float v[4];
#pragma unroll
            for (int j = 0; j < 4; ++j) {
                float x = acc[i][half * 4 + j];
                int col = col0 + j;
                if (bias && col < N) x += bias[col];
                if (act == 1) x = gelu_f(x);
                v[j] = x;
            }
            if (col0 + 4 <= N) {
                *(float4*)(C + (size_t)row * N + col0) = make_float4(v[0], v[1], v[2], v[3]);
            } else {
#pragma unroll
                for (int j = 0; j < 4; ++j)
                    if (col0 + j < N) C[(size_t)row * N + col0 + j] = v[j];
            }
        }
    }
}

// ---------------- fused gelu + layernorm (in-place, 128 cols) ----------------
__global__ void gelu_ln_kernel(float* __restrict__ h, const float* __restrict__ g,
                               const float* __restrict__ b) {
    int row = blockIdx.x, t = threadIdx.x;
    float* hp = h + (size_t)row * HID;
    float x = gelu_f(hp[t]);
    __shared__ float red[2];
    float s = x;
#pragma unroll
    for (int off = 32; off > 0; off >>= 1) s += __shfl_xor(s, off);
    if ((t & 63) == 0) red[t >> 6] = s;
    __syncthreads();
    float mean = (red[0] + red[1]) * (1.0f / 128.0f);
    float d = x - mean;
    float vs = d * d;
    __syncthreads();
#pragma unroll
    for (int off = 32; off > 0; off >>= 1) vs += __shfl_xor(vs, off);
    if ((t & 63) == 0) red[t >> 6] = vs;
    __syncthreads();
    float var = (red[0] + red[1]) * (1.0f / 128.0f);
    hp[t] = d / sqrtf(var + 1e-5f) * g[t] + b[t];
}

// ---------------- CSR build (dst-indexed) ----------------
__global__ void hist_kernel(const int* __restrict__ dst, int* __restrict__ deg, int e) {
    int i = blockIdx.x * blockDim.x + threadIdx.x;
    if (i < e) atomicAdd(&deg[dst[i]], 1);
}

__global__ void scan_kernel(const int* __restrict__ deg, int* __restrict__ row_start,
                            int* __restrict__ cursor, int n) {
    __shared__ int wsum[16];
    __shared__ int chunk_total;
    int t = threadIdx.x;
    int lane = t & 63, wv = t >> 6;
    int carry = 0;
    for (int base = 0; base < n; base += 8192) {
        int idx0 = base + t * 8;
        int v[8];
        int s = 0;
#pragma unroll
        for (int u = 0; u < 8; ++u) {
            int d = (idx0 + u < n) ? deg[idx0 + u] : 0;
            v[u] = s;
            s += d;
        }
        int ws = s;
#pragma unroll
        for (int off = 1; off < 64; off <<= 1) {
            int u2 = __shfl_up(ws, off);
            if (lane >= off) ws += u2;
        }
        if (lane == 63) wsum[wv] = ws;
        __syncthreads();
        if (t == 0) {
            int a = 0;
#pragma unroll
            for (int k = 0; k < 16; ++k) {
                int tmp = wsum[k];
                wsum[k] = a;
                a += tmp;
            }
            chunk_total = a;
        }
        __syncthreads();
        int excl = ws - s + wsum[wv] + carry;
#pragma unroll
        for (int u = 0; u < 8; ++u) {
            if (idx0 + u < n) {
                row_start[idx0 + u] = excl + v[u];
                cursor[idx0 + u] = excl + v[u];
            }
        }
        carry += chunk_total;
        __syncthreads();
    }
    if (t == 0) row_start[n] = carry;
}

__global__ void scatter_kernel(const int* __restrict__ src, const int* __restrict__ dst,
                               const int* __restrict__ et, int* __restrict__ cursor,
                               int* __restrict__ csr_src, int* __restrict__ csr_de, int e) {
    int i = blockIdx.x * blockDim.x + threadIdx.x;
    if (i < e) {
        int d = dst[i];
        int pos = atomicAdd(&cursor[d], 1);
        csr_src[pos] = src[i];
        csr_de[pos] = d | (et[i] << 20);
    }
}

// ---------------- per-(node,head) attention dots ----------------
__global__ void esed_kernel(const float* __restrict__ q, const float* __restrict__ asrc,
                            const float* __restrict__ adst, float* __restrict__ es,
                            float* __restrict__ ed, int nn) {
    int idx = blockIdx.x * blockDim.x + threadIdx.x;
    if (idx >= nn * 4) return;
    int n = idx >> 2, hh = idx & 3;
    const float* qp = q + (size_t)n * HID + hh * DHD;
    const float* ap = asrc + hh * DHD;
    const float* dp = adst + hh * DHD;
    float s = 0.f, d = 0.f;
#pragma unroll
    for (int k = 0; k < DHD; ++k) {
        float qv = qp[k];
        s += qv * ap[k];
        d += qv * dp[k];
    }
    es[idx] = s;
    ed[idx] = d;
}

// ---------------- per-CSR-slot logits (4 heads) ----------------
__global__ void lg_kernel(const int* __restrict__ csr_src, const int* __restrict__ csr_de,
                          const float* __restrict__ es, const float* __restrict__ ed,
                          const float* __restrict__ etb, float* __restrict__ lg_csr, int e) {
    int pos = blockIdx.x * blockDim.x + threadIdx.x;
    if (pos >= e) return;
    int s = csr_src[pos];
    int de = csr_de[pos];
    int d = de & 0xFFFFF;
    int et = de >> 20;
    float4 esv = *(const float4*)(es + (size_t)s * 4);
    float4 edv = *(const float4*)(ed + (size_t)d * 4);
    float4 bv  = *(const float4*)(etb + (size_t)et * 4);
    float l0 = esv.x + edv.x + bv.x;
    float l1 = esv.y + edv.y + bv.y;
    float l2 = esv.z + edv.z + bv.z;
    float l3 = esv.w + edv.w + bv.w;
    l0 = l0 > 0.f ? l0 : 0.2f * l0;
    l1 = l1 > 0.f ? l1 : 0.2f * l1;
    l2 = l2 > 0.f ? l2 : 0.2f * l2;
    l3 = l3 > 0.f ? l3 : 0.2f * l3;
    *(float4*)(lg_csr + (size_t)pos * 4) = make_float4(l0, l1, l2, l3);
}

// ---------------- per-(node,head) softmax max/denominator ----------------
__global__ void mden_kernel(const float* __restrict__ lg_csr, const int* __restrict__ row_start,
                            float* __restrict__ m_arr, float* __restrict__ den_arr, int nn) {
    int idx = blockIdx.x * blockDim.x + threadIdx.x;
    if (idx >= nn * 4) return;
    int n = idx >> 2, hh = idx & 3;
    int e0 = row_start[n], e1 = row_start[n + 1];
    float m = -INFINITY;
    for (int e = e0; e < e1; ++e) m = fmaxf(m, lg_csr[(size_t)e * 4 + hh]);
    if (e0 == e1) m = 0.f;
    float den = 0.f;
    for (int e = e0; e < e1; ++e) den += expf(lg_csr[(size_t)e * 4 + hh] - m);
    m_arr[idx] = m;
    den_arr[idx] = den;
}

// ---------------- per-(edge,head) alpha (in-place over lg) ----------------
__global__ void alpha_kernel(float* __restrict__ lg_csr, const int* __restrict__ csr_de,
                             const float* __restrict__ m_arr, const float* __restrict__ den_arr,
                             int e) {
    int idx = blockIdx.x * blockDim.x + threadIdx.x;
    if (idx >= e * 4) return;
    int pos = idx >> 2, hh = idx & 3;
    int d = csr_de[pos] & 0xFFFFF;
    float a = expf(lg_csr[idx] - m_arr[(size_t)d * 4 + hh]) /
              (den_arr[(size_t)d * 4 + hh] + 1e-9f);
    lg_csr[idx] = a;
}

// ---------------- GAT aggregation: pure alpha * q gather-FMA ----------------
__global__ void gat_agg_kernel(const float* __restrict__ q, const float* __restrict__ r,
                               const float* __restrict__ alpha_csr,
                               const int* __restrict__ row_start, const int* __restrict__ csr_src,
                               float* __restrict__ hout, int nn) {
    int n = blockIdx.x;
    int t = threadIdx.x;
    int hh = t >> 5;
    int e0 = row_start[n], e1 = row_start[n + 1];
    float acc = 0.f;
    for (int e = e0; e < e1; ++e) {
        int s = csr_src[e];
        float al = alpha_csr[(size_t)e * 4 + hh];
        acc += al * q[(size_t)s * HID + t];
    }
    float v = acc + r[(size_t)n * HID + t];
    hout[(size_t)n * HID + t] = v > 0.f ? v : expm1f(v);
}

// ---------------- final scaling + clip ----------------
__global__ void final_kernel(const float* __restrict__ y, const float* __restrict__ hs,
                             const float* __restrict__ gs, const int* __restrict__ dept_ids,
                             const float* __restrict__ hm, float* __restrict__ out, int nn) {
    int idx = blockIdx.x * blockDim.x + threadIdx.x;
    if (idx >= nn * 28) return;
    int n = idx / 28, j = idx - n * 28;
    float v = y[idx] * softplus_f(hs[j]) * softplus_f(gs[dept_ids[n]]);
    float hi = 20.0f * hm[n];
    out[idx] = fminf(fmaxf(v, 0.0f), hi);
}

extern "C" void kernel_launch(void* const* d_in, const int* in_sizes, int n_in,
                              void* d_out, int out_size, void* d_ws, size_t ws_size,
                              hipStream_t stream) {
    const float* nf       = (const float*)d_in[0];
    const int*   eidx     = (const int*)d_in[1];
    const int*   etype    = (const int*)d_in[2];
    const int*   store_id = (const int*)d_in[3];
    const int*   dept_id  = (const int*)d_in[4];
    const int*   cat_id   = (const int*)d_in[5];
    const int*   state_id = (const int*)d_in[6];
    const int*   item_id  = (const int*)d_in[7];
    const int*   dept_ids = (const int*)d_in[8];
    const float* hm       = (const float*)d_in[9];
    const float* e_store  = (const float*)d_in[10];
    const float* e_dept   = (const float*)d_in[11];
    const float* e_cat    = (const float*)d_in[12];
    const float* e_state  = (const float*)d_in[13];
    const float* e_item   = (const float*)d_in[14];
    const float* fusion_W = (const float*)d_in[15];
    const float* fusion_b = (const float*)d_in[16];
    const float* ln_g     = (const float*)d_in[17];
    const float* ln_b     = (const float*)d_in[18];
    const float* gat_W    = (const float*)d_in[19];
    const float* gat_b    = (const float*)d_in[20];
    const float* gat_asrc = (const float*)d_in[21];
    const float* gat_adst = (const float*)d_in[22];
    const float* gat_et   = (const float*)d_in[23];
    const float* gat_Wres = (const float*)d_in[24];
    const float* pW1      = (const float*)d_in[25];
    const float* pb1      = (const float*)d_in[26];
    const float* pW2      = (const float*)d_in[27];
    const float* pb2      = (const float*)d_in[28];
    const float* pW3      = (const float*)d_in[29];
    const float* pb3      = (const float*)d_in[30];
    const float* hs       = (const float*)d_in[31];
    const float* gs       = (const float*)d_in[32];

    const int nn = in_sizes[3];   // 30490
    const int ee = in_sizes[2];   // 487840
    const int* src = eidx;
    const int* dst = eidx + ee;

    // workspace layout
    float* ws = (float*)d_ws;
    float* X   = ws;                               // nn x 292
    float* h   = X + (size_t)nn * 292;             // nn x 128
    float* q   = h + (size_t)nn * 128;             // nn x 128
    float* r   = q + (size_t)nn * 128;             // nn x 128
    float* t2  = r + (size_t)nn * 128;             // nn x 256
    float* es  = t2 + (size_t)nn * 256;            // nn x 4
    float* ed  = es + (size_t)nn * 4;              // nn x 4
    float* m_a = ed + (size_t)nn * 4;              // nn x 4
    float* d_a = m_a + (size_t)nn * 4;             // nn x 4
    float* lg  = d_a + (size_t)nn * 4;             // ee x 4
    int* deg       = (int*)(lg + (size_t)ee * 4);  // nn
    int* row_start = deg + nn;                     // nn+1
    int* cursor    = row_start + nn + 1;           // nn
    int* csr_src   = cursor + nn;                  // ee
    int* csr_de    = csr_src + ee;                 // ee
    float* t1 = X;                                 // reuse
    float* y  = q;                                 // reuse

    const int gx = (nn + 63) / 64;

    // --- CSR build ---
    hipMemsetAsync(deg, 0, nn * sizeof(int), stream);
    hist_kernel<<<(ee + 255) / 256, 256, 0, stream>>>(dst, deg, ee);
    scan_kernel<<<1, 1024, 0, stream>>>(deg, row_start, cursor, nn);
    scatter_kernel<<<(ee + 255) / 256, 256, 0, stream>>>(src, dst, etype, cursor,
                                                         csr_src, csr_de, ee);

    // --- features ---
    dim3 sg((nn + 255) / 256, 3);
    sig_kernel<<<sg, 256, 0, stream>>>(nf, X, nn);
    emb_kernel<<<(nn + 255) / 256, 256, 0, stream>>>(X, store_id, dept_id, cat_id, state_id,
                                                     item_id, e_store, e_dept, e_cat, e_state,
                                                     e_item, nn);

    // --- fusion + LN ---
    gemm_db_kernel<<<dim3(gx, 1), 256, 0, stream>>>(
        X, nn, 292, fusion_W, fusion_b, h, 128, 0, 1,
        nullptr, nullptr, nullptr, 0, 0);
    gelu_ln_kernel<<<nn, 128, 0, stream>>>(h, ln_g, ln_b);

    // --- 3 GAT layers ---
    for (int l = 0; l < 3; ++l) {
        // q = h@W + b  and  r = h@Wres in ONE dispatch (shared A)
        gemm_db_kernel<<<dim3(gx, 2), 256, 0, stream>>>(
            h, nn, 128,
            gat_W + (size_t)l * 128 * 128, gat_b + l * 128, q, 128, 0, 1,
            gat_Wres + (size_t)l * 128 * 128, nullptr, r, 128, 0);
        esed_kernel<<<(nn * 4 + 255) / 256, 256, 0, stream>>>(q, gat_asrc + l * 128,
                                                              gat_adst + l * 128, es, ed, nn);
        lg_kernel<<<(ee + 255) / 256, 256, 0, stream>>>(csr_src, csr_de, es, ed,
                                                        gat_et + l * 12, lg, ee);
        mden_kernel<<<(nn * 4 + 255) / 256, 256, 0, stream>>>(lg, row_start, m_a, d_a, nn);
        alpha_kernel<<<(ee * 4 + 255) / 256, 256, 0, stream>>>(lg, csr_de, m_a, d_a, ee);
        gat_agg_kernel<<<nn, 128, 0, stream>>>(q, r, lg, row_start, csr_src, h, nn);
    }

    // --- prediction MLP ---
    gemm_db_kernel<<<dim3(gx, 2), 256, 0, stream>>>(
        h, nn, 128, pW1, pb1, t1, 256, 1, 2,
        nullptr, nullptr, nullptr, 0, 0);
    gemm_db_kernel<<<dim3(gx, 2), 256, 0, stream>>>(
        t1, nn, 256, pW2, pb2, t2, 256, 1, 2,
        nullptr, nullptr, nullptr, 0, 0);
    gemm_db_kernel<<<dim3(gx, 1), 256, 0, stream>>>(
        t2, nn, 256, pW3, pb3, y, 28, 0, 1,
        nullptr, nullptr, nullptr, 0, 0);
    final_kernel<<<(nn * 28 + 255) / 256, 256, 0, stream>>>(y, hs, gs, dept_ids, hm,
                                                            (float*)d_out, nn);
}